// Round 5
// baseline (413.611 us; speedup 1.0000x reference)
//
#include <hip/hip_runtime.h>

// LengthAdaptor: B=16, T=512, C_IN=512, C_HID=256, C_EMB=384, K=5, MAX_DUR=8
// Outputs (concat, f32): x_up [16,4096,512] | ldp [16,512] | emb_up [16,4096,384]
//
// R4b: pure-bf16 MFMA convs with LN fused in-block (Ntile=256 full width,
// Mtile=32, 4 waves, 2 blocks/CU). No Ksplit, no partials round-trip.
// conv1 -> h1 bf16 directly; conv2 -> fused linear+mask -> ldp.
// Gather uses nontemporal stores (235 MB streaming writes) via native
// ext_vector float4 (HIP_vector_type float4 is rejected by the builtin).

constexpr int Bn = 16, Tn = 512, CIN1 = 512, CHID = 256, CEMB = 384, MAXMEL = 4096;
constexpr int NROWS = Bn * Tn;
#define LRELU 0.3f
#define EPSV 1e-5f

typedef __attribute__((ext_vector_type(8))) short bf16x8;
typedef __attribute__((ext_vector_type(4))) float f32x4;
typedef unsigned short ushort_t;

static __device__ __forceinline__ ushort_t f2bf(float f) {
  unsigned u = __builtin_bit_cast(unsigned, f);
  unsigned r = (u + 0x7fffu + ((u >> 16) & 1u)) >> 16;  // RNE
  return (ushort_t)r;
}

// ---------------------------------------------------------------------------
// Weight prep: w [5][CI][256] f32 -> fragment-contiguous bf16.
// frag fr = (ksh*(CI/32)+ci32)*16 + cob ; frag[l][j] =
//   W[ksh][ci32*32 + (l>>4)*8 + j][cob*16 + (l&15)]
// ---------------------------------------------------------------------------
__global__ __launch_bounds__(256) void wprep_kernel(const float* __restrict__ w,
                                                    ushort_t* __restrict__ hi,
                                                    int CI) {
  const int gid = blockIdx.x * 256 + threadIdx.x;
  const int ksh = gid / (CI * 256);
  const int rem = gid - ksh * CI * 256;
  const int ci = rem >> 8, co = rem & 255;
  const int ci32 = ci >> 5, cob = co >> 4;
  const int l = ((ci >> 3) & 3) * 16 + (co & 15);
  const int j = ci & 7;
  const size_t dst = ((size_t)((ksh * (CI / 32) + ci32) * 16 + cob)) * 512 + l * 8 + j;
  hi[dst] = f2bf(w[gid]);
}

// ---------------------------------------------------------------------------
// Fused conv1d(K=5) + bias + leaky-relu + LayerNorm (+ linear head).
// Grid 256 (Mtile=32 rows, full 256 cols). Block 256 = 4 waves, wave 32x64
// (im=2 x jn=4, acc 32 VGPR). A in LDS (36 rows x 64ci chunk, stride 72).
// B from L2 (fragment-contiguous). Epilogue: acc->LDS, in-block LN.
// ---------------------------------------------------------------------------
template <int CI, bool F32IN>
__global__ __launch_bounds__(256, 2) void conv_ln_mfma_kernel(
    const float* __restrict__ xin,        // F32IN: [8192][CI] f32
    const ushort_t* __restrict__ inbf,    // !F32IN: [8192][CI] bf16
    const ushort_t* __restrict__ wB,      // fragment-contiguous bf16
    const float* __restrict__ bias, const float* __restrict__ g,
    const float* __restrict__ be,
    ushort_t* __restrict__ h1out,         // !FINAL (conv1)
    const float* __restrict__ lw, const float* __restrict__ lb,
    const unsigned char* __restrict__ mask, float* __restrict__ ldp) {
  constexpr bool FINAL = !F32IN;
  constexpr int NCHUNK = CI / 64;
  constexpr int LDSTRIDE = 72;
  __shared__ ushort_t sA[36 * LDSTRIDE];
  __shared__ float sC[32 * 260];          // 33.3 KB acc buffer (stride 260)
  __shared__ float sps[32 * 8], spq[32 * 8];
  __shared__ float smu[32], srs[32];

  const int b = blockIdx.x >> 4, t0 = (blockIdx.x & 15) * 32;
  const int tid = threadIdx.x;
  const int l = tid & 63, nh = tid >> 6;  // wave = col group
  const int lm = l & 15, lq = l >> 4;

  f32x4 acc[2][4];
#pragma unroll
  for (int im = 0; im < 2; ++im)
#pragma unroll
    for (int jn = 0; jn < 4; ++jn) acc[im][jn] = (f32x4){0.f, 0.f, 0.f, 0.f};

  const ushort_t* pB = wB + l * 8;

#pragma unroll 1
  for (int chunk = 0; chunk < NCHUNK; ++chunk) {
    // ---- stage 36 rows x 64 ci ----
    {
      const int cibase = chunk * 64;
#pragma unroll 1
      for (int i = 0; i < 5; ++i) {       // 5*256 >= 1152 uint pairs
        const int p = i * 256 + tid;
        if (p < 36 * 32) {
          const int r = p >> 5, c2 = (p & 31) * 2;
          const int t = t0 - 2 + r;
          unsigned hv = 0;
          if ((unsigned)t < (unsigned)Tn) {
            const size_t src = (size_t)(b * Tn + t) * CI + cibase + c2;
            if (F32IN) {
              const float2 v = *(const float2*)(xin + src);
              hv = (unsigned)f2bf(v.x) | ((unsigned)f2bf(v.y) << 16);
            } else {
              hv = *(const unsigned*)(inbf + src);
            }
          }
          *(unsigned*)&sA[r * LDSTRIDE + c2] = hv;
        }
      }
    }
    __syncthreads();

#pragma unroll 1
    for (int ksh = 0; ksh < 5; ++ksh) {
#pragma unroll
      for (int kk = 0; kk < 2; ++kk) {
        bf16x8 a[2];
#pragma unroll
        for (int im = 0; im < 2; ++im)
          a[im] = *(const bf16x8*)&sA[(im * 16 + lm + ksh) * LDSTRIDE + kk * 32 + lq * 8];
        const int frBase = (ksh * (CI / 32) + chunk * 2 + kk) * 16 + nh * 4;
#pragma unroll
        for (int jn = 0; jn < 4; ++jn) {
          const bf16x8 bv = *(const bf16x8*)(pB + (size_t)(frBase + jn) * 512);
#pragma unroll
          for (int im = 0; im < 2; ++im)
            acc[im][jn] = __builtin_amdgcn_mfma_f32_16x16x32_bf16(a[im], bv, acc[im][jn], 0, 0, 0);
        }
      }
    }
    __syncthreads();
  }

  // ---- epilogue: acc -> sC (D: col=lane&15, row=(lane>>4)*4+reg) ----
#pragma unroll
  for (int im = 0; im < 2; ++im)
#pragma unroll
    for (int jn = 0; jn < 4; ++jn) {
      const int col = nh * 64 + jn * 16 + lm;
#pragma unroll
      for (int reg = 0; reg < 4; ++reg)
        sC[(im * 16 + lq * 4 + reg) * 260 + col] = acc[im][jn][reg];
    }
  __syncthreads();

  // ---- LN: thread = (row = tid>>3, 32-col segment sg = tid&7) ----
  const int row = tid >> 3, sg = tid & 7;
  float v[32];
  float s = 0.f, s2 = 0.f;
#pragma unroll
  for (int q = 0; q < 8; ++q) {
    const f32x4 c4 = *(const f32x4*)&sC[row * 260 + sg * 32 + q * 4];
    const f32x4 b4 = ((const f32x4*)bias)[sg * 8 + q];
    float x0 = c4.x + b4.x, x1 = c4.y + b4.y, x2 = c4.z + b4.z, x3 = c4.w + b4.w;
    x0 = (x0 > 0.f) ? x0 : LRELU * x0;
    x1 = (x1 > 0.f) ? x1 : LRELU * x1;
    x2 = (x2 > 0.f) ? x2 : LRELU * x2;
    x3 = (x3 > 0.f) ? x3 : LRELU * x3;
    v[q * 4] = x0; v[q * 4 + 1] = x1; v[q * 4 + 2] = x2; v[q * 4 + 3] = x3;
    s += x0 + x1 + x2 + x3;
    s2 += x0 * x0 + x1 * x1 + x2 * x2 + x3 * x3;
  }
  sps[row * 8 + sg] = s;
  spq[row * 8 + sg] = s2;
  __syncthreads();
  if (tid < 32) {
    float ts = 0.f, tq = 0.f;
#pragma unroll
    for (int q = 0; q < 8; ++q) { ts += sps[tid * 8 + q]; tq += spq[tid * 8 + q]; }
    const float mu = ts * (1.f / 256.f);
    const float var = tq * (1.f / 256.f) - mu * mu;
    smu[tid] = mu;
    srs[tid] = rsqrtf(var + EPSV);
  }
  __syncthreads();
  const float mu = smu[row], rs = srs[row];
  const int rowg = b * Tn + t0 + row;

  if (!FINAL) {
    unsigned up[16];
#pragma unroll
    for (int q = 0; q < 8; ++q) {
      const f32x4 g4 = ((const f32x4*)g)[sg * 8 + q];
      const f32x4 e4 = ((const f32x4*)be)[sg * 8 + q];
      const float h0 = (v[q * 4] - mu) * rs * g4.x + e4.x;
      const float h1 = (v[q * 4 + 1] - mu) * rs * g4.y + e4.y;
      const float h2 = (v[q * 4 + 2] - mu) * rs * g4.z + e4.z;
      const float h3 = (v[q * 4 + 3] - mu) * rs * g4.w + e4.w;
      up[q * 2] = (unsigned)f2bf(h0) | ((unsigned)f2bf(h1) << 16);
      up[q * 2 + 1] = (unsigned)f2bf(h2) | ((unsigned)f2bf(h3) << 16);
    }
    uint4* dst = (uint4*)(h1out + (size_t)rowg * 256 + sg * 32);
#pragma unroll
    for (int q = 0; q < 4; ++q)
      dst[q] = make_uint4(up[q * 4], up[q * 4 + 1], up[q * 4 + 2], up[q * 4 + 3]);
  } else {
    float d = 0.f;
#pragma unroll
    for (int q = 0; q < 8; ++q) {
      const f32x4 g4 = ((const f32x4*)g)[sg * 8 + q];
      const f32x4 e4 = ((const f32x4*)be)[sg * 8 + q];
      const f32x4 l4 = ((const f32x4*)lw)[sg * 8 + q];
      d += ((v[q * 4] - mu) * rs * g4.x + e4.x) * l4.x;
      d += ((v[q * 4 + 1] - mu) * rs * g4.y + e4.y) * l4.y;
      d += ((v[q * 4 + 2] - mu) * rs * g4.z + e4.z) * l4.z;
      d += ((v[q * 4 + 3] - mu) * rs * g4.w + e4.w) * l4.w;
    }
    sps[row * 8 + sg] = d;
    __syncthreads();
    if (tid < 32) {
      float td = 0.f;
#pragma unroll
      for (int q = 0; q < 8; ++q) td += sps[tid * 8 + q];
      float val = td + lb[0];
      if (mask[b * Tn + t0 + tid]) val = 0.f;
      ldp[b * Tn + t0 + tid] = val;
    }
  }
}

// ---------------------------------------------------------------------------
// Length regulation
// ---------------------------------------------------------------------------
__global__ __launch_bounds__(512) void build_idx_kernel(const int* __restrict__ dur,
                                                        int* __restrict__ idx) {
  __shared__ int cum[Tn];
  const int b = blockIdx.x, t = threadIdx.x;
  const int d = dur[b * Tn + t];
  cum[t] = d;
  __syncthreads();
  for (int off = 1; off < Tn; off <<= 1) {
    int v = (t >= off) ? cum[t - off] : 0;
    __syncthreads();
    cum[t] += v;
    __syncthreads();
  }
  const int end = cum[t];
  for (int p = end - d; p < end; ++p) idx[b * MAXMEL + p] = t;
  const int total = cum[Tn - 1];
  for (int p = total + t; p < MAXMEL; p += Tn) idx[b * MAXMEL + p] = -1;
}

__global__ __launch_bounds__(256) void gather_kernel(const float* __restrict__ x,
                                                     const float* __restrict__ emb,
                                                     const int* __restrict__ idx,
                                                     float* __restrict__ x_up,
                                                     float* __restrict__ emb_up) {
  const f32x4* x4 = (const f32x4*)x;
  const f32x4* e4 = (const f32x4*)emb;
  f32x4* xu4 = (f32x4*)x_up;
  f32x4* eu4 = (f32x4*)emb_up;
  const int tid0 = blockIdx.x * 256 + threadIdx.x;
  const int stride = gridDim.x * 256;
  const f32x4 z = (f32x4){0.f, 0.f, 0.f, 0.f};
  for (int u = tid0; u < Bn * MAXMEL * 128; u += stride) {
    const int bp = u >> 7, i = u & 127;
    const int t = idx[bp];
    const int b = bp >> 12;
    const f32x4 v = (t >= 0) ? x4[((b << 9) + t) * 128 + i] : z;
    __builtin_nontemporal_store(v, &xu4[u]);
  }
  for (int u = tid0; u < Bn * MAXMEL * 96; u += stride) {
    const int bp = u / 96, i = u - bp * 96;
    const int t = idx[bp];
    const int b = bp >> 12;
    const f32x4 v = (t >= 0) ? e4[((b << 9) + t) * 96 + i] : z;
    __builtin_nontemporal_store(v, &eu4[u]);
  }
}

// ---------------------------------------------------------------------------
extern "C" void kernel_launch(void* const* d_in, const int* in_sizes, int n_in,
                              void* d_out, int out_size, void* d_ws, size_t ws_size,
                              hipStream_t stream) {
  const float* x     = (const float*)d_in[0];
  const float* x_res = (const float*)d_in[1];
  const int*   dur   = (const int*)d_in[2];
  const float* emb   = (const float*)d_in[3];
  const unsigned char* mask = (const unsigned char*)d_in[4];
  const float* c1w = (const float*)d_in[5];
  const float* c1b = (const float*)d_in[6];
  const float* g1  = (const float*)d_in[7];
  const float* b1  = (const float*)d_in[8];
  const float* c2w = (const float*)d_in[9];
  const float* c2b = (const float*)d_in[10];
  const float* g2  = (const float*)d_in[11];
  const float* b2  = (const float*)d_in[12];
  const float* lw  = (const float*)d_in[13];
  const float* lb  = (const float*)d_in[14];

  float* x_up   = (float*)d_out;
  float* ldp    = x_up + (size_t)Bn * MAXMEL * CIN1;
  float* emb_up = ldp + (size_t)Bn * Tn;

  // All scratch in ws: idx 256KB | h1 4MB | w1 1.31MB | w2 0.66MB = 6.2MB
  int* idx = (int*)d_ws;
  ushort_t* h1 = (ushort_t*)((char*)d_ws + (size_t)Bn * MAXMEL * 4);
  ushort_t* w1 = h1 + (size_t)NROWS * 256;
  ushort_t* w2 = w1 + (size_t)5 * 512 * 256;

  wprep_kernel<<<5 * 512 * 256 / 256, 256, 0, stream>>>(c1w, w1, 512);
  wprep_kernel<<<5 * 256 * 256 / 256, 256, 0, stream>>>(c2w, w2, 256);
  build_idx_kernel<<<Bn, Tn, 0, stream>>>(dur, idx);
  conv_ln_mfma_kernel<512, true><<<256, 256, 0, stream>>>(
      x_res, nullptr, w1, c1b, g1, b1, h1, nullptr, nullptr, nullptr, nullptr);
  conv_ln_mfma_kernel<256, false><<<256, 256, 0, stream>>>(
      nullptr, h1, w2, c2b, g2, b2, nullptr, lw, lb, mask, ldp);
  gather_kernel<<<2048, 256, 0, stream>>>(x, emb, idx, x_up, emb_up);
}

// Round 6
// 371.194 us; speedup vs baseline: 1.1143x; 1.1143x over previous
//
#include <hip/hip_runtime.h>

// LengthAdaptor: B=16, T=512, C_IN=512, C_HID=256, C_EMB=384, K=5, MAX_DUR=8
// Outputs (concat, f32): x_up [16,4096,512] | ldp [16,512] | emb_up [16,4096,384]
//
// R6: convs use mfma_f32_32x32x16_bf16, block tile 32x128 (4 waves x one
// 32x32 chain), grid 512 = 2 blocks/CU. Full-K per block (no partials);
// separate streaming LN kernels. XOR-swizzled LDS A staging. Gather with NT
// stores. conv scratch (pre-activation f32, 16 MB) lives in emb_up region.

constexpr int Bn = 16, Tn = 512, CIN1 = 512, CHID = 256, CEMB = 384, MAXMEL = 4096;
constexpr int NROWS = Bn * Tn;
#define LRELU 0.3f
#define EPSV 1e-5f

typedef __attribute__((ext_vector_type(8))) short bf16x8;
typedef __attribute__((ext_vector_type(4))) float f32x4;
typedef __attribute__((ext_vector_type(16))) float f32x16;
typedef unsigned short ushort_t;

static __device__ __forceinline__ ushort_t f2bf(float f) {
  unsigned u = __builtin_bit_cast(unsigned, f);
  unsigned r = (u + 0x7fffu + ((u >> 16) & 1u)) >> 16;  // RNE
  return (ushort_t)r;
}

// ---------------------------------------------------------------------------
// Weight prep: w [5][CI][256] f32 -> 32x32x16-fragment-contiguous bf16.
// frag fr = (ksh*(CI/16)+ci16)*8 + cob32; lane l, j:
//   element (ci = ci16*16 + (l>>5)*8 + j, co = cob32*32 + (l&31))
// ---------------------------------------------------------------------------
__global__ __launch_bounds__(256) void wprep_kernel(const float* __restrict__ w,
                                                    ushort_t* __restrict__ out,
                                                    int CI) {
  const int gid = blockIdx.x * 256 + threadIdx.x;
  const int ksh = gid / (CI * 256);
  const int rem = gid - ksh * CI * 256;
  const int ci = rem >> 8, co = rem & 255;
  const int ci16 = ci >> 4, cob32 = co >> 5;
  const int l = ((ci >> 3) & 1) * 32 + (co & 31);
  const int j = ci & 7;
  const size_t dst = ((size_t)((ksh * (CI / 16) + ci16) * 8 + cob32)) * 512 + l * 8 + j;
  out[dst] = f2bf(w[gid]);
}

// ---------------------------------------------------------------------------
// Conv MFMA kernel (32x32x16). grid (mt=256, ns=2), block 256 = 4 waves.
// Block tile 32 rows x 128 cols; wave = one 32x32 acc (16 VGPR).
// A staged in LDS (36 rows x 64ci chunk, stride 72 ushorts, XOR swizzle).
// B direct from L2 (fragment-contiguous). Writes pre-activation f32.
// ---------------------------------------------------------------------------
template <int CI, bool F32IN>
__global__ __launch_bounds__(256, 2) void conv_mfma_kernel(
    const float* __restrict__ xin,        // F32IN: [8192][CI] f32
    const ushort_t* __restrict__ inbf,    // !F32IN: [8192][CI] bf16
    const ushort_t* __restrict__ wB,      // fragment-contiguous bf16
    float* __restrict__ hraw) {           // [8192][256] f32 (full sums)
  constexpr int NCHUNK = CI / 64;
  constexpr int ROWS = 36, LDSTRIDE = 72;
  __shared__ ushort_t sA[ROWS * LDSTRIDE];

  const int mt = blockIdx.x, ns = blockIdx.y;
  const int b = mt >> 4, t0 = (mt & 15) * 32;
  const int tid = threadIdx.x;
  const int l = tid & 63, nh = tid >> 6;
  const int lm = l & 31, lq = l >> 5;     // lane row / k-half
  const int cob32 = ns * 4 + nh;

  f32x16 acc;
#pragma unroll
  for (int i = 0; i < 16; ++i) acc[i] = 0.f;

  const ushort_t* pB = wB + (size_t)cob32 * 512 + l * 8;

#pragma unroll 1
  for (int chunk = 0; chunk < NCHUNK; ++chunk) {
    // ---- stage 36 rows x 64 ci (uint-pair writes, XOR swizzle) ----
    {
      const int cibase = chunk * 64;
#pragma unroll 1
      for (int i = 0; i < 5; ++i) {       // 5*256 >= 1152 pairs
        const int p = i * 256 + tid;
        if (p < ROWS * 32) {
          const int r = p >> 5, c2 = (p & 31) * 2;
          const int t = t0 - 2 + r;
          unsigned hv = 0;
          if ((unsigned)t < (unsigned)Tn) {
            const size_t src = (size_t)(b * Tn + t) * CI + cibase + c2;
            if (F32IN) {
              const float2 v = *(const float2*)(xin + src);
              hv = (unsigned)f2bf(v.x) | ((unsigned)f2bf(v.y) << 16);
            } else {
              hv = *(const unsigned*)(inbf + src);
            }
          }
          const int sw = ((r >> 3) & 3) << 3;
          *(unsigned*)&sA[r * LDSTRIDE + (c2 ^ sw)] = hv;
        }
      }
    }
    __syncthreads();

#pragma unroll 1
    for (int ksh = 0; ksh < 5; ++ksh) {
      const int r = lm + ksh;
      const int sw = ((r >> 3) & 3) << 3;
      const size_t bbase = (size_t)((ksh * (CI / 16) + chunk * 4) * 8) * 512;
#pragma unroll
      for (int kk = 0; kk < 4; ++kk) {
        const int c = (kk * 16 + lq * 8) ^ sw;
        const bf16x8 a = *(const bf16x8*)&sA[r * LDSTRIDE + c];
        const bf16x8 bv = *(const bf16x8*)(pB + bbase + (size_t)kk * 8 * 512);
        acc = __builtin_amdgcn_mfma_f32_32x32x16_bf16(a, bv, acc, 0, 0, 0);
      }
    }
    __syncthreads();
  }

  // ---- D: col = lane&31, row = (reg&3) + 8*(reg>>2) + 4*(lane>>5) ----
  const int col = ns * 128 + nh * 32 + lm;
  float* pOut = hraw + (size_t)(b * Tn + t0) * 256 + col;
#pragma unroll
  for (int reg = 0; reg < 16; ++reg) {
    const int row = (reg & 3) + 8 * (reg >> 2) + 4 * lq;
    pOut[(size_t)row * 256] = acc[reg];
  }
}

// ---------------------------------------------------------------------------
// bias + leaky-relu + LayerNorm. One wave per row, grid 2048.
// FINAL=false: emit h1 bf16. FINAL=true: fused linear(256->1) + mask -> ldp.
// ---------------------------------------------------------------------------
template <bool FINAL>
__global__ __launch_bounds__(256) void ln_kernel(
    const float* __restrict__ hraw,       // [8192][256] f32
    const float* __restrict__ bias, const float* __restrict__ g,
    const float* __restrict__ be, ushort_t* __restrict__ h1,
    const float* __restrict__ lw, const float* __restrict__ lb,
    const unsigned char* __restrict__ mask, float* __restrict__ ldp) {
  const int row = blockIdx.x * 4 + (threadIdx.x >> 6);
  const int l = threadIdx.x & 63;
  const f32x4 p = ((const f32x4*)hraw)[row * 64 + l];
  const f32x4 bi = ((const f32x4*)bias)[l];
  float v0 = p.x + bi.x, v1 = p.y + bi.y, v2 = p.z + bi.z, v3 = p.w + bi.w;
  v0 = (v0 > 0.f) ? v0 : LRELU * v0;
  v1 = (v1 > 0.f) ? v1 : LRELU * v1;
  v2 = (v2 > 0.f) ? v2 : LRELU * v2;
  v3 = (v3 > 0.f) ? v3 : LRELU * v3;
  float s = v0 + v1 + v2 + v3;
  float s2 = v0 * v0 + v1 * v1 + v2 * v2 + v3 * v3;
#pragma unroll
  for (int off = 32; off >= 1; off >>= 1) {
    s += __shfl_xor(s, off);
    s2 += __shfl_xor(s2, off);
  }
  const float mu = s * (1.f / 256.f);
  const float var = s2 * (1.f / 256.f) - mu * mu;
  const float rs = rsqrtf(var + EPSV);
  const f32x4 gg = ((const f32x4*)g)[l];
  const f32x4 bb = ((const f32x4*)be)[l];
  const float h0 = (v0 - mu) * rs * gg.x + bb.x;
  const float h1v = (v1 - mu) * rs * gg.y + bb.y;
  const float h2 = (v2 - mu) * rs * gg.z + bb.z;
  const float h3 = (v3 - mu) * rs * gg.w + bb.w;
  if (!FINAL) {
    ushort4 uh;
    uh.x = f2bf(h0); uh.y = f2bf(h1v); uh.z = f2bf(h2); uh.w = f2bf(h3);
    ((ushort4*)h1)[row * 64 + l] = uh;
  } else {
    const f32x4 lv = ((const f32x4*)lw)[l];
    float d = h0 * lv.x + h1v * lv.y + h2 * lv.z + h3 * lv.w;
#pragma unroll
    for (int off = 32; off >= 1; off >>= 1) d += __shfl_xor(d, off);
    if (l == 0) {
      float val = d + lb[0];
      if (mask[row]) val = 0.f;
      ldp[row] = val;
    }
  }
}

// ---------------------------------------------------------------------------
// Length regulation
// ---------------------------------------------------------------------------
__global__ __launch_bounds__(512) void build_idx_kernel(const int* __restrict__ dur,
                                                        int* __restrict__ idx) {
  __shared__ int cum[Tn];
  const int b = blockIdx.x, t = threadIdx.x;
  const int d = dur[b * Tn + t];
  cum[t] = d;
  __syncthreads();
  for (int off = 1; off < Tn; off <<= 1) {
    int v = (t >= off) ? cum[t - off] : 0;
    __syncthreads();
    cum[t] += v;
    __syncthreads();
  }
  const int end = cum[t];
  for (int p = end - d; p < end; ++p) idx[b * MAXMEL + p] = t;
  const int total = cum[Tn - 1];
  for (int p = total + t; p < MAXMEL; p += Tn) idx[b * MAXMEL + p] = -1;
}

__global__ __launch_bounds__(256) void gather_kernel(const float* __restrict__ x,
                                                     const float* __restrict__ emb,
                                                     const int* __restrict__ idx,
                                                     float* __restrict__ x_up,
                                                     float* __restrict__ emb_up) {
  const f32x4* x4 = (const f32x4*)x;
  const f32x4* e4 = (const f32x4*)emb;
  f32x4* xu4 = (f32x4*)x_up;
  f32x4* eu4 = (f32x4*)emb_up;
  const int tid0 = blockIdx.x * 256 + threadIdx.x;
  const int stride = gridDim.x * 256;
  const f32x4 z = (f32x4){0.f, 0.f, 0.f, 0.f};
  for (int u = tid0; u < Bn * MAXMEL * 128; u += stride) {
    const int bp = u >> 7, i = u & 127;
    const int t = idx[bp];
    const int b = bp >> 12;
    const f32x4 v = (t >= 0) ? x4[((b << 9) + t) * 128 + i] : z;
    __builtin_nontemporal_store(v, &xu4[u]);
  }
  for (int u = tid0; u < Bn * MAXMEL * 96; u += stride) {
    const int bp = u / 96, i = u - bp * 96;
    const int t = idx[bp];
    const int b = bp >> 12;
    const f32x4 v = (t >= 0) ? e4[((b << 9) + t) * 96 + i] : z;
    __builtin_nontemporal_store(v, &eu4[u]);
  }
}

// ---------------------------------------------------------------------------
extern "C" void kernel_launch(void* const* d_in, const int* in_sizes, int n_in,
                              void* d_out, int out_size, void* d_ws, size_t ws_size,
                              hipStream_t stream) {
  const float* x     = (const float*)d_in[0];
  const float* x_res = (const float*)d_in[1];
  const int*   dur   = (const int*)d_in[2];
  const float* emb   = (const float*)d_in[3];
  const unsigned char* mask = (const unsigned char*)d_in[4];
  const float* c1w = (const float*)d_in[5];
  const float* c1b = (const float*)d_in[6];
  const float* g1  = (const float*)d_in[7];
  const float* b1  = (const float*)d_in[8];
  const float* c2w = (const float*)d_in[9];
  const float* c2b = (const float*)d_in[10];
  const float* g2  = (const float*)d_in[11];
  const float* b2  = (const float*)d_in[12];
  const float* lw  = (const float*)d_in[13];
  const float* lb  = (const float*)d_in[14];

  float* x_up   = (float*)d_out;
  float* ldp    = x_up + (size_t)Bn * MAXMEL * CIN1;
  float* emb_up = ldp + (size_t)Bn * Tn;

  // hraw (16 MB f32) in emb_up region of d_out — overwritten last by gather.
  float* hraw = emb_up;

  // ws: idx 256KB | h1 4MB | w1 1.31MB | w2 0.66MB = 6.2MB (proven footprint)
  int* idx = (int*)d_ws;
  ushort_t* h1 = (ushort_t*)((char*)d_ws + (size_t)Bn * MAXMEL * 4);
  ushort_t* w1 = h1 + (size_t)NROWS * 256;
  ushort_t* w2 = w1 + (size_t)5 * 512 * 256;

  wprep_kernel<<<5 * 512 * 256 / 256, 256, 0, stream>>>(c1w, w1, 512);
  wprep_kernel<<<5 * 256 * 256 / 256, 256, 0, stream>>>(c2w, w2, 256);
  build_idx_kernel<<<Bn, Tn, 0, stream>>>(dur, idx);
  conv_mfma_kernel<512, true><<<dim3(256, 2), 256, 0, stream>>>(
      x_res, nullptr, w1, hraw);
  ln_kernel<false><<<NROWS / 4, 256, 0, stream>>>(
      hraw, c1b, g1, b1, h1, nullptr, nullptr, nullptr, nullptr);
  conv_mfma_kernel<256, false><<<dim3(256, 2), 256, 0, stream>>>(
      nullptr, h1, w2, hraw);
  ln_kernel<true><<<NROWS / 4, 256, 0, stream>>>(
      hraw, c2b, g2, b2, nullptr, lw, lb, mask, ldp);
  gather_kernel<<<2048, 256, 0, stream>>>(x, emb, idx, x_up, emb_up);
}

// Round 7
// 359.672 us; speedup vs baseline: 1.1500x; 1.0320x over previous
//
#include <hip/hip_runtime.h>

// LengthAdaptor: B=16, T=512, C_IN=512, C_HID=256, C_EMB=384, K=5, MAX_DUR=8
// Outputs (concat, f32): x_up [16,4096,512] | ldp [16,512] | emb_up [16,4096,384]
//
// R7: R6 structure (32x32x16 MFMA convs, 2 blocks/CU, separate LN) plus:
//  - wprep: fragment-per-wave with coalesced 1KB stores, both weights fused
//  - build_idx: shfl_up wave scan (2 barriers)
//  - conv chunks 128 ci (half the barriers)
//  - hraw scratch in d_ws

constexpr int Bn = 16, Tn = 512, CIN1 = 512, CHID = 256, CEMB = 384, MAXMEL = 4096;
constexpr int NROWS = Bn * Tn;
#define LRELU 0.3f
#define EPSV 1e-5f

typedef __attribute__((ext_vector_type(8))) short bf16x8;
typedef __attribute__((ext_vector_type(4))) float f32x4;
typedef __attribute__((ext_vector_type(16))) float f32x16;
typedef __attribute__((ext_vector_type(4))) unsigned int u32x4;
typedef unsigned short ushort_t;

static __device__ __forceinline__ ushort_t f2bf(float f) {
  unsigned u = __builtin_bit_cast(unsigned, f);
  unsigned r = (u + 0x7fffu + ((u >> 16) & 1u)) >> 16;  // RNE
  return (ushort_t)r;
}

// ---------------------------------------------------------------------------
// Weight prep (both convs, one dispatch). Fragment fr = (ksh*(CI/16)+ci16)*8
// + cob32; lane l supplies B[k = ci16*16 + (l>>5)*8 + j][n = cob32*32+(l&31)]
// for j=0..7 as 16 contiguous bytes -> 1KB coalesced store per wave-fragment.
// w1: 1280 fragments (blocks 0..319), w2: 640 fragments (blocks 320..479).
// ---------------------------------------------------------------------------
__global__ __launch_bounds__(256) void wprep_kernel(const float* __restrict__ w1src,
                                                    const float* __restrict__ w2src,
                                                    ushort_t* __restrict__ w1dst,
                                                    ushort_t* __restrict__ w2dst) {
  const int blk = blockIdx.x;
  const float* src;
  ushort_t* dst;
  int CI, fr0, sh;
  if (blk < 320) { src = w1src; dst = w1dst; CI = 512; sh = 5; fr0 = blk * 4; }
  else           { src = w2src; dst = w2dst; CI = 256; sh = 4; fr0 = (blk - 320) * 4; }
  const int wv = threadIdx.x >> 6, l = threadIdx.x & 63;
  const int fr = fr0 + wv;
  const int cob32 = fr & 7;
  const int t = fr >> 3;                 // ksh*(CI/16) + ci16
  const int ksh = t >> sh;
  const int ci16 = t & ((1 << sh) - 1);
  const int ci = ci16 * 16 + (l >> 5) * 8;
  const int co = cob32 * 32 + (l & 31);
  ushort_t v[8];
#pragma unroll
  for (int j = 0; j < 8; ++j)
    v[j] = f2bf(src[((size_t)(ksh * CI + ci + j)) * 256 + co]);
  u32x4 pack;
#pragma unroll
  for (int q = 0; q < 4; ++q)
    pack[q] = (unsigned)v[q * 2] | ((unsigned)v[q * 2 + 1] << 16);
  *(u32x4*)&dst[(size_t)fr * 512 + l * 8] = pack;
}

// ---------------------------------------------------------------------------
// Conv MFMA kernel (32x32x16). grid (mt=256, ns=2), block 256 = 4 waves.
// Block tile 32 rows x 128 cols; wave = one 32x32 acc chain (16 VGPR).
// A staged per 128-ci chunk in LDS (36 x 136 ushorts, XOR swizzle).
// B direct from L2 (fragment-contiguous). Writes pre-activation f32.
// ---------------------------------------------------------------------------
template <int CI, bool F32IN>
__global__ __launch_bounds__(256, 2) void conv_mfma_kernel(
    const float* __restrict__ xin,        // F32IN: [8192][CI] f32
    const ushort_t* __restrict__ inbf,    // !F32IN: [8192][CI] bf16
    const ushort_t* __restrict__ wB,      // fragment-contiguous bf16
    float* __restrict__ hraw) {           // [8192][256] f32 (full sums)
  constexpr int NCHUNK = CI / 128;
  constexpr int ROWS = 36, LDSTRIDE = 136;
  __shared__ ushort_t sA[ROWS * LDSTRIDE];

  const int mt = blockIdx.x, ns = blockIdx.y;
  const int b = mt >> 4, t0 = (mt & 15) * 32;
  const int tid = threadIdx.x;
  const int l = tid & 63, nh = tid >> 6;
  const int lm = l & 31, lq = l >> 5;
  const int cob32 = ns * 4 + nh;

  f32x16 acc;
#pragma unroll
  for (int i = 0; i < 16; ++i) acc[i] = 0.f;

  const ushort_t* pB = wB + (size_t)cob32 * 512 + l * 8;

#pragma unroll 1
  for (int chunk = 0; chunk < NCHUNK; ++chunk) {
    // ---- stage 36 rows x 128 ci (2304 uint-pairs, 9 iters) ----
    {
      const int cibase = chunk * 128;
#pragma unroll 1
      for (int i = 0; i < 9; ++i) {
        const int p = i * 256 + tid;      // 9*256 = 2304 = 36*64 exact
        const int r = p >> 6, c2 = (p & 63) * 2;
        const int t = t0 - 2 + r;
        unsigned hv = 0;
        if ((unsigned)t < (unsigned)Tn) {
          const size_t src = (size_t)(b * Tn + t) * CI + cibase + c2;
          if (F32IN) {
            const float2 v = *(const float2*)(xin + src);
            hv = (unsigned)f2bf(v.x) | ((unsigned)f2bf(v.y) << 16);
          } else {
            hv = *(const unsigned*)(inbf + src);
          }
        }
        const int sw = ((r >> 3) & 3) << 3;
        *(unsigned*)&sA[r * LDSTRIDE + (c2 ^ sw)] = hv;
      }
    }
    __syncthreads();

#pragma unroll 1
    for (int ksh = 0; ksh < 5; ++ksh) {
      const int r = lm + ksh;
      const int sw = ((r >> 3) & 3) << 3;
      const size_t bbase = (size_t)((ksh * (CI / 16) + chunk * 8) * 8) * 512;
#pragma unroll
      for (int kk = 0; kk < 8; ++kk) {
        const int c = (kk * 16 + lq * 8) ^ sw;
        const bf16x8 a = *(const bf16x8*)&sA[r * LDSTRIDE + c];
        const bf16x8 bv = *(const bf16x8*)(pB + bbase + (size_t)kk * 8 * 512);
        acc = __builtin_amdgcn_mfma_f32_32x32x16_bf16(a, bv, acc, 0, 0, 0);
      }
    }
    __syncthreads();
  }

  // ---- D: col = lane&31, row = (reg&3) + 8*(reg>>2) + 4*(lane>>5) ----
  const int col = ns * 128 + nh * 32 + lm;
  float* pOut = hraw + (size_t)(b * Tn + t0) * 256 + col;
#pragma unroll
  for (int reg = 0; reg < 16; ++reg) {
    const int row = (reg & 3) + 8 * (reg >> 2) + 4 * lq;
    pOut[(size_t)row * 256] = acc[reg];
  }
}

// ---------------------------------------------------------------------------
// bias + leaky-relu + LayerNorm. One wave per row, grid 2048.
// FINAL=false: emit h1 bf16. FINAL=true: fused linear(256->1) + mask -> ldp.
// ---------------------------------------------------------------------------
template <bool FINAL>
__global__ __launch_bounds__(256) void ln_kernel(
    const float* __restrict__ hraw,       // [8192][256] f32
    const float* __restrict__ bias, const float* __restrict__ g,
    const float* __restrict__ be, ushort_t* __restrict__ h1,
    const float* __restrict__ lw, const float* __restrict__ lb,
    const unsigned char* __restrict__ mask, float* __restrict__ ldp) {
  const int row = blockIdx.x * 4 + (threadIdx.x >> 6);
  const int l = threadIdx.x & 63;
  const f32x4 p = ((const f32x4*)hraw)[row * 64 + l];
  const f32x4 bi = ((const f32x4*)bias)[l];
  float v0 = p.x + bi.x, v1 = p.y + bi.y, v2 = p.z + bi.z, v3 = p.w + bi.w;
  v0 = (v0 > 0.f) ? v0 : LRELU * v0;
  v1 = (v1 > 0.f) ? v1 : LRELU * v1;
  v2 = (v2 > 0.f) ? v2 : LRELU * v2;
  v3 = (v3 > 0.f) ? v3 : LRELU * v3;
  float s = v0 + v1 + v2 + v3;
  float s2 = v0 * v0 + v1 * v1 + v2 * v2 + v3 * v3;
#pragma unroll
  for (int off = 32; off >= 1; off >>= 1) {
    s += __shfl_xor(s, off);
    s2 += __shfl_xor(s2, off);
  }
  const float mu = s * (1.f / 256.f);
  const float var = s2 * (1.f / 256.f) - mu * mu;
  const float rs = rsqrtf(var + EPSV);
  const f32x4 gg = ((const f32x4*)g)[l];
  const f32x4 bb = ((const f32x4*)be)[l];
  const float h0 = (v0 - mu) * rs * gg.x + bb.x;
  const float h1v = (v1 - mu) * rs * gg.y + bb.y;
  const float h2 = (v2 - mu) * rs * gg.z + bb.z;
  const float h3 = (v3 - mu) * rs * gg.w + bb.w;
  if (!FINAL) {
    ushort4 uh;
    uh.x = f2bf(h0); uh.y = f2bf(h1v); uh.z = f2bf(h2); uh.w = f2bf(h3);
    ((ushort4*)h1)[row * 64 + l] = uh;
  } else {
    const f32x4 lv = ((const f32x4*)lw)[l];
    float d = h0 * lv.x + h1v * lv.y + h2 * lv.z + h3 * lv.w;
#pragma unroll
    for (int off = 32; off >= 1; off >>= 1) d += __shfl_xor(d, off);
    if (l == 0) {
      float val = d + lb[0];
      if (mask[row]) val = 0.f;
      ldp[row] = val;
    }
  }
}

// ---------------------------------------------------------------------------
// Length regulation: shfl_up wave scan + LDS combine (2 barriers).
// ---------------------------------------------------------------------------
__global__ __launch_bounds__(512) void build_idx_kernel(const int* __restrict__ dur,
                                                        int* __restrict__ idx) {
  __shared__ int wsum[8];
  const int b = blockIdx.x, tid = threadIdx.x;
  const int lane = tid & 63, wv = tid >> 6;
  const int d = dur[b * Tn + tid];
  int v = d;
#pragma unroll
  for (int off = 1; off <= 32; off <<= 1) {
    const int t = __shfl_up(v, off);
    if (lane >= off) v += t;
  }
  if (lane == 63) wsum[wv] = v;
  __syncthreads();
  int woff = 0, total = 0;
#pragma unroll
  for (int i = 0; i < 8; ++i) {
    const int s = wsum[i];
    if (i < wv) woff += s;
    total += s;
  }
  const int end = v + woff;               // inclusive cumsum
  for (int p = end - d; p < end; ++p) idx[b * MAXMEL + p] = tid;
  for (int p = total + tid; p < MAXMEL; p += 512) idx[b * MAXMEL + p] = -1;
}

__global__ __launch_bounds__(256) void gather_kernel(const float* __restrict__ x,
                                                     const float* __restrict__ emb,
                                                     const int* __restrict__ idx,
                                                     float* __restrict__ x_up,
                                                     float* __restrict__ emb_up) {
  const f32x4* x4 = (const f32x4*)x;
  const f32x4* e4 = (const f32x4*)emb;
  f32x4* xu4 = (f32x4*)x_up;
  f32x4* eu4 = (f32x4*)emb_up;
  const int tid0 = blockIdx.x * 256 + threadIdx.x;
  const int stride = gridDim.x * 256;
  const f32x4 z = (f32x4){0.f, 0.f, 0.f, 0.f};
  for (int u = tid0; u < Bn * MAXMEL * 128; u += stride) {
    const int bp = u >> 7, i = u & 127;
    const int t = idx[bp];
    const int b = bp >> 12;
    const f32x4 v = (t >= 0) ? x4[((b << 9) + t) * 128 + i] : z;
    __builtin_nontemporal_store(v, &xu4[u]);
  }
  for (int u = tid0; u < Bn * MAXMEL * 96; u += stride) {
    const int bp = u / 96, i = u - bp * 96;
    const int t = idx[bp];
    const int b = bp >> 12;
    const f32x4 v = (t >= 0) ? e4[((b << 9) + t) * 96 + i] : z;
    __builtin_nontemporal_store(v, &eu4[u]);
  }
}

// ---------------------------------------------------------------------------
extern "C" void kernel_launch(void* const* d_in, const int* in_sizes, int n_in,
                              void* d_out, int out_size, void* d_ws, size_t ws_size,
                              hipStream_t stream) {
  const float* x     = (const float*)d_in[0];
  const float* x_res = (const float*)d_in[1];
  const int*   dur   = (const int*)d_in[2];
  const float* emb   = (const float*)d_in[3];
  const unsigned char* mask = (const unsigned char*)d_in[4];
  const float* c1w = (const float*)d_in[5];
  const float* c1b = (const float*)d_in[6];
  const float* g1  = (const float*)d_in[7];
  const float* b1  = (const float*)d_in[8];
  const float* c2w = (const float*)d_in[9];
  const float* c2b = (const float*)d_in[10];
  const float* g2  = (const float*)d_in[11];
  const float* b2  = (const float*)d_in[12];
  const float* lw  = (const float*)d_in[13];
  const float* lb  = (const float*)d_in[14];

  float* x_up   = (float*)d_out;
  float* ldp    = x_up + (size_t)Bn * MAXMEL * CIN1;
  float* emb_up = ldp + (size_t)Bn * Tn;

  // ws layout: idx 256KB | h1 4MB | w1 1.31MB | w2 0.66MB | hraw 8MB ≈ 14.5MB
  int* idx = (int*)d_ws;
  ushort_t* h1 = (ushort_t*)((char*)d_ws + (size_t)Bn * MAXMEL * 4);
  ushort_t* w1 = h1 + (size_t)NROWS * 256;
  ushort_t* w2 = w1 + (size_t)5 * 512 * 256;
  float* hraw = (float*)(w2 + (size_t)5 * 256 * 256);

  wprep_kernel<<<480, 256, 0, stream>>>(c1w, c2w, w1, w2);
  build_idx_kernel<<<Bn, 512, 0, stream>>>(dur, idx);
  conv_mfma_kernel<512, true><<<dim3(256, 2), 256, 0, stream>>>(
      x_res, nullptr, w1, hraw);
  ln_kernel<false><<<NROWS / 4, 256, 0, stream>>>(
      hraw, c1b, g1, b1, h1, nullptr, nullptr, nullptr, nullptr);
  conv_mfma_kernel<256, false><<<dim3(256, 2), 256, 0, stream>>>(
      nullptr, h1, w2, hraw);
  ln_kernel<true><<<NROWS / 4, 256, 0, stream>>>(
      hraw, c2b, g2, b2, nullptr, lw, lb, mask, ldp);
  gather_kernel<<<2048, 256, 0, stream>>>(x, emb, idx, x_up, emb_up);
}

// Round 8
// 353.080 us; speedup vs baseline: 1.1714x; 1.0187x over previous
//
#include <hip/hip_runtime.h>

// LengthAdaptor: B=16, T=512, C_IN=512, C_HID=256, C_EMB=384, K=5, MAX_DUR=8
// Outputs (concat, f32): x_up [16,4096,512] | ldp [16,512] | emb_up [16,4096,384]
//
// R8: block-specialized fusion to overlap the HBM-bound gather with the
// compute-bound conv1 in a single dispatch (blocks 0..511 conv1 at 2/CU,
// blocks 512..2559 gather grid-stride filling spare wave slots).
// Prep (wprep + build_idx) fused likewise. 5 dispatches total.
// Conv structure from R7: 32x32x16 MFMA, 128-ci chunks, XOR-swizzled LDS A,
// fragment-contiguous B from L2.

constexpr int Bn = 16, Tn = 512, CIN1 = 512, CHID = 256, CEMB = 384, MAXMEL = 4096;
constexpr int NROWS = Bn * Tn;
#define LRELU 0.3f
#define EPSV 1e-5f

typedef __attribute__((ext_vector_type(8))) short bf16x8;
typedef __attribute__((ext_vector_type(4))) float f32x4;
typedef __attribute__((ext_vector_type(16))) float f32x16;
typedef __attribute__((ext_vector_type(4))) unsigned int u32x4;
typedef unsigned short ushort_t;

static __device__ __forceinline__ ushort_t f2bf(float f) {
  unsigned u = __builtin_bit_cast(unsigned, f);
  unsigned r = (u + 0x7fffu + ((u >> 16) & 1u)) >> 16;  // RNE
  return (ushort_t)r;
}

// ---------------------------------------------------------------------------
// Conv MFMA body (32x32x16). Block tile 32 rows x 128 cols, 4 waves, each one
// 32x32 acc chain. A staged per 128-ci chunk in LDS (XOR swizzle); B direct
// from L2 (fragment-contiguous). Writes pre-activation f32 to hraw.
// ---------------------------------------------------------------------------
template <int CI, bool F32IN>
static __device__ __forceinline__ void conv_body(
    int mt, int ns,
    const float* __restrict__ xin, const ushort_t* __restrict__ inbf,
    const ushort_t* __restrict__ wB, float* __restrict__ hraw) {
  constexpr int NCHUNK = CI / 128;
  constexpr int ROWS = 36, LDSTRIDE = 136;
  __shared__ ushort_t sA[ROWS * LDSTRIDE];

  const int b = mt >> 4, t0 = (mt & 15) * 32;
  const int tid = threadIdx.x;
  const int l = tid & 63, nh = tid >> 6;
  const int lm = l & 31, lq = l >> 5;
  const int cob32 = ns * 4 + nh;

  f32x16 acc;
#pragma unroll
  for (int i = 0; i < 16; ++i) acc[i] = 0.f;

  const ushort_t* pB = wB + (size_t)cob32 * 512 + l * 8;

#pragma unroll 1
  for (int chunk = 0; chunk < NCHUNK; ++chunk) {
    {
      const int cibase = chunk * 128;
#pragma unroll 1
      for (int i = 0; i < 9; ++i) {
        const int p = i * 256 + tid;      // 9*256 = 2304 = 36*64 exact
        const int r = p >> 6, c2 = (p & 63) * 2;
        const int t = t0 - 2 + r;
        unsigned hv = 0;
        if ((unsigned)t < (unsigned)Tn) {
          const size_t src = (size_t)(b * Tn + t) * CI + cibase + c2;
          if (F32IN) {
            const float2 v = *(const float2*)(xin + src);
            hv = (unsigned)f2bf(v.x) | ((unsigned)f2bf(v.y) << 16);
          } else {
            hv = *(const unsigned*)(inbf + src);
          }
        }
        const int sw = ((r >> 3) & 3) << 3;
        *(unsigned*)&sA[r * LDSTRIDE + (c2 ^ sw)] = hv;
      }
    }
    __syncthreads();

#pragma unroll 1
    for (int ksh = 0; ksh < 5; ++ksh) {
      const int r = lm + ksh;
      const int sw = ((r >> 3) & 3) << 3;
      const size_t bbase = (size_t)((ksh * (CI / 16) + chunk * 8) * 8) * 512;
#pragma unroll
      for (int kk = 0; kk < 8; ++kk) {
        const int c = (kk * 16 + lq * 8) ^ sw;
        const bf16x8 a = *(const bf16x8*)&sA[r * LDSTRIDE + c];
        const bf16x8 bv = *(const bf16x8*)(pB + bbase + (size_t)kk * 8 * 512);
        acc = __builtin_amdgcn_mfma_f32_32x32x16_bf16(a, bv, acc, 0, 0, 0);
      }
    }
    __syncthreads();
  }

  // D: col = lane&31, row = (reg&3) + 8*(reg>>2) + 4*(lane>>5)
  const int col = ns * 128 + nh * 32 + lm;
  float* pOut = hraw + (size_t)(b * Tn + t0) * 256 + col;
#pragma unroll
  for (int reg = 0; reg < 16; ++reg) {
    const int row = (reg & 3) + 8 * (reg >> 2) + 4 * lq;
    pOut[(size_t)row * 256] = acc[reg];
  }
}

// ---------------------------------------------------------------------------
// Dispatch B: conv1 (blocks 0..511) + gather (blocks 512..2559).
// ---------------------------------------------------------------------------
__global__ __launch_bounds__(256, 2) void conv1_gather_kernel(
    const float* __restrict__ x_res, const ushort_t* __restrict__ w1,
    float* __restrict__ hraw,
    const float* __restrict__ x, const float* __restrict__ emb,
    const int* __restrict__ idx,
    float* __restrict__ x_up, float* __restrict__ emb_up) {
  const int blk = blockIdx.x;
  if (blk < 512) {
    conv_body<512, true>(blk & 255, blk >> 8, x_res, nullptr, w1, hraw);
    return;
  }
  // ---- gather path ----
  const f32x4* x4 = (const f32x4*)x;
  const f32x4* e4 = (const f32x4*)emb;
  f32x4* xu4 = (f32x4*)x_up;
  f32x4* eu4 = (f32x4*)emb_up;
  const int tid0 = (blk - 512) * 256 + threadIdx.x;
  const int stride = 2048 * 256;
  const f32x4 z = (f32x4){0.f, 0.f, 0.f, 0.f};
  for (int u = tid0; u < Bn * MAXMEL * 128; u += stride) {
    const int bp = u >> 7, i = u & 127;
    const int t = idx[bp];
    const int b = bp >> 12;
    const f32x4 v = (t >= 0) ? x4[((b << 9) + t) * 128 + i] : z;
    __builtin_nontemporal_store(v, &xu4[u]);
  }
  for (int u = tid0; u < Bn * MAXMEL * 96; u += stride) {
    const int bp = u / 96, i = u - bp * 96;
    const int t = idx[bp];
    const int b = bp >> 12;
    const f32x4 v = (t >= 0) ? e4[((b << 9) + t) * 96 + i] : z;
    __builtin_nontemporal_store(v, &eu4[u]);
  }
}

// ---------------------------------------------------------------------------
// Dispatch D: conv2 alone (grid 512 flat).
// ---------------------------------------------------------------------------
__global__ __launch_bounds__(256, 2) void conv2_kernel(
    const ushort_t* __restrict__ h1, const ushort_t* __restrict__ w2,
    float* __restrict__ hraw) {
  const int blk = blockIdx.x;
  conv_body<256, false>(blk & 255, blk >> 8, nullptr, h1, w2, hraw);
}

// ---------------------------------------------------------------------------
// bias + leaky-relu + LayerNorm. One wave per row, grid 2048.
// FINAL=false: emit h1 bf16. FINAL=true: fused linear(256->1) + mask -> ldp.
// ---------------------------------------------------------------------------
template <bool FINAL>
__global__ __launch_bounds__(256) void ln_kernel(
    const float* __restrict__ hraw,       // [8192][256] f32
    const float* __restrict__ bias, const float* __restrict__ g,
    const float* __restrict__ be, ushort_t* __restrict__ h1,
    const float* __restrict__ lw, const float* __restrict__ lb,
    const unsigned char* __restrict__ mask, float* __restrict__ ldp) {
  const int row = blockIdx.x * 4 + (threadIdx.x >> 6);
  const int l = threadIdx.x & 63;
  const f32x4 p = ((const f32x4*)hraw)[row * 64 + l];
  const f32x4 bi = ((const f32x4*)bias)[l];
  float v0 = p.x + bi.x, v1 = p.y + bi.y, v2 = p.z + bi.z, v3 = p.w + bi.w;
  v0 = (v0 > 0.f) ? v0 : LRELU * v0;
  v1 = (v1 > 0.f) ? v1 : LRELU * v1;
  v2 = (v2 > 0.f) ? v2 : LRELU * v2;
  v3 = (v3 > 0.f) ? v3 : LRELU * v3;
  float s = v0 + v1 + v2 + v3;
  float s2 = v0 * v0 + v1 * v1 + v2 * v2 + v3 * v3;
#pragma unroll
  for (int off = 32; off >= 1; off >>= 1) {
    s += __shfl_xor(s, off);
    s2 += __shfl_xor(s2, off);
  }
  const float mu = s * (1.f / 256.f);
  const float var = s2 * (1.f / 256.f) - mu * mu;
  const float rs = rsqrtf(var + EPSV);
  const f32x4 gg = ((const f32x4*)g)[l];
  const f32x4 bb = ((const f32x4*)be)[l];
  const float h0 = (v0 - mu) * rs * gg.x + bb.x;
  const float h1v = (v1 - mu) * rs * gg.y + bb.y;
  const float h2 = (v2 - mu) * rs * gg.z + bb.z;
  const float h3 = (v3 - mu) * rs * gg.w + bb.w;
  if (!FINAL) {
    ushort4 uh;
    uh.x = f2bf(h0); uh.y = f2bf(h1v); uh.z = f2bf(h2); uh.w = f2bf(h3);
    ((ushort4*)h1)[row * 64 + l] = uh;
  } else {
    const f32x4 lv = ((const f32x4*)lw)[l];
    float d = h0 * lv.x + h1v * lv.y + h2 * lv.z + h3 * lv.w;
#pragma unroll
    for (int off = 32; off >= 1; off >>= 1) d += __shfl_xor(d, off);
    if (l == 0) {
      float val = d + lb[0];
      if (mask[row]) val = 0.f;
      ldp[row] = val;
    }
  }
}

// ---------------------------------------------------------------------------
// Dispatch A: weight prep (blocks 0..239, 8 frags/block) + build_idx
// (blocks 240..255). 512 threads.
// wprep: fragment fr=(ksh*(CI/16)+ci16)*8+cob32; lane l gives 8 k's x 1 n:
//   k = ci16*16+(l>>5)*8+j, n = cob32*32+(l&31); 1KB coalesced store/wave.
// ---------------------------------------------------------------------------
__global__ __launch_bounds__(512) void prep_kernel(
    const float* __restrict__ w1src, const float* __restrict__ w2src,
    ushort_t* __restrict__ w1dst, ushort_t* __restrict__ w2dst,
    const int* __restrict__ dur, int* __restrict__ idx) {
  __shared__ int wsum[8];
  const int blk = blockIdx.x;
  const int tid = threadIdx.x;
  if (blk < 240) {
    const float* src;
    ushort_t* dst;
    int CI, fr, sh;
    const int wv = tid >> 6, l = tid & 63;
    if (blk < 160) { src = w1src; dst = w1dst; CI = 512; sh = 5; fr = blk * 8 + wv; }
    else           { src = w2src; dst = w2dst; CI = 256; sh = 4; fr = (blk - 160) * 8 + wv; }
    const int cob32 = fr & 7;
    const int t = fr >> 3;
    const int ksh = t >> sh;
    const int ci16 = t & ((1 << sh) - 1);
    const int ci = ci16 * 16 + (l >> 5) * 8;
    const int co = cob32 * 32 + (l & 31);
    ushort_t v[8];
#pragma unroll
    for (int j = 0; j < 8; ++j)
      v[j] = f2bf(src[((size_t)(ksh * CI + ci + j)) * 256 + co]);
    u32x4 pack;
#pragma unroll
    for (int q = 0; q < 4; ++q)
      pack[q] = (unsigned)v[q * 2] | ((unsigned)v[q * 2 + 1] << 16);
    *(u32x4*)&dst[(size_t)fr * 512 + l * 8] = pack;
    return;
  }
  // ---- build_idx path ----
  const int b = blk - 240;
  const int lane = tid & 63, wv = tid >> 6;
  const int d = dur[b * Tn + tid];
  int v = d;
#pragma unroll
  for (int off = 1; off <= 32; off <<= 1) {
    const int t = __shfl_up(v, off);
    if (lane >= off) v += t;
  }
  if (lane == 63) wsum[wv] = v;
  __syncthreads();
  int woff = 0, total = 0;
#pragma unroll
  for (int i = 0; i < 8; ++i) {
    const int s = wsum[i];
    if (i < wv) woff += s;
    total += s;
  }
  const int end = v + woff;               // inclusive cumsum
  for (int p = end - d; p < end; ++p) idx[b * MAXMEL + p] = tid;
  for (int p = total + tid; p < MAXMEL; p += 512) idx[b * MAXMEL + p] = -1;
}

// ---------------------------------------------------------------------------
extern "C" void kernel_launch(void* const* d_in, const int* in_sizes, int n_in,
                              void* d_out, int out_size, void* d_ws, size_t ws_size,
                              hipStream_t stream) {
  const float* x     = (const float*)d_in[0];
  const float* x_res = (const float*)d_in[1];
  const int*   dur   = (const int*)d_in[2];
  const float* emb   = (const float*)d_in[3];
  const unsigned char* mask = (const unsigned char*)d_in[4];
  const float* c1w = (const float*)d_in[5];
  const float* c1b = (const float*)d_in[6];
  const float* g1  = (const float*)d_in[7];
  const float* b1  = (const float*)d_in[8];
  const float* c2w = (const float*)d_in[9];
  const float* c2b = (const float*)d_in[10];
  const float* g2  = (const float*)d_in[11];
  const float* b2  = (const float*)d_in[12];
  const float* lw  = (const float*)d_in[13];
  const float* lb  = (const float*)d_in[14];

  float* x_up   = (float*)d_out;
  float* ldp    = x_up + (size_t)Bn * MAXMEL * CIN1;
  float* emb_up = ldp + (size_t)Bn * Tn;

  // ws layout: idx 256KB | h1 4MB | w1 1.31MB | w2 0.66MB | hraw 8MB ≈ 14.5MB
  int* idx = (int*)d_ws;
  ushort_t* h1 = (ushort_t*)((char*)d_ws + (size_t)Bn * MAXMEL * 4);
  ushort_t* w1 = h1 + (size_t)NROWS * 256;
  ushort_t* w2 = w1 + (size_t)5 * 512 * 256;
  float* hraw = (float*)(w2 + (size_t)5 * 256 * 256);

  prep_kernel<<<256, 512, 0, stream>>>(c1w, c2w, w1, w2, dur, idx);
  conv1_gather_kernel<<<2560, 256, 0, stream>>>(
      x_res, w1, hraw, x, emb, idx, x_up, emb_up);
  ln_kernel<false><<<NROWS / 4, 256, 0, stream>>>(
      hraw, c1b, g1, b1, h1, nullptr, nullptr, nullptr, nullptr);
  conv2_kernel<<<512, 256, 0, stream>>>(h1, w2, hraw);
  ln_kernel<true><<<NROWS / 4, 256, 0, stream>>>(
      hraw, c2b, g2, b2, nullptr, lw, lb, mask, ldp);
}

// Round 9
// 347.769 us; speedup vs baseline: 1.1893x; 1.0153x over previous
//
#include <hip/hip_runtime.h>

// LengthAdaptor: B=16, T=512, C_IN=512, C_HID=256, C_EMB=384, K=5, MAX_DUR=8
// Outputs (concat, f32): x_up [16,4096,512] | ldp [16,512] | emb_up [16,4096,384]
//
// R9: interleaved block-type mixing. Dispatch2 = conv1 + x_up gather,
// dispatch4 = conv2 + emb_up gather, with conv assigned to blk%3==0 so the
// co-resident set on each CU mixes MFMA waves with HBM-streaming waves from
// t=0 (R8 put all conv blocks first -> serial execution, no overlap).
// Conv structure from R7: 32x32x16 MFMA, 128-ci chunks, XOR-swizzled LDS A,
// fragment-contiguous B from L2. 5 dispatches.

constexpr int Bn = 16, Tn = 512, CIN1 = 512, CHID = 256, CEMB = 384, MAXMEL = 4096;
constexpr int NROWS = Bn * Tn;
#define LRELU 0.3f
#define EPSV 1e-5f

typedef __attribute__((ext_vector_type(8))) short bf16x8;
typedef __attribute__((ext_vector_type(4))) float f32x4;
typedef __attribute__((ext_vector_type(16))) float f32x16;
typedef __attribute__((ext_vector_type(4))) unsigned int u32x4;
typedef unsigned short ushort_t;

static __device__ __forceinline__ ushort_t f2bf(float f) {
  unsigned u = __builtin_bit_cast(unsigned, f);
  unsigned r = (u + 0x7fffu + ((u >> 16) & 1u)) >> 16;  // RNE
  return (ushort_t)r;
}

// ---------------------------------------------------------------------------
// Conv MFMA body (32x32x16). Block tile 32 rows x 128 cols, 4 waves, each one
// 32x32 acc chain. A staged per 128-ci chunk in LDS (XOR swizzle); B direct
// from L2 (fragment-contiguous). Writes pre-activation f32 to hraw.
// ---------------------------------------------------------------------------
template <int CI, bool F32IN>
static __device__ __forceinline__ void conv_body(
    int mt, int ns,
    const float* __restrict__ xin, const ushort_t* __restrict__ inbf,
    const ushort_t* __restrict__ wB, float* __restrict__ hraw) {
  constexpr int NCHUNK = CI / 128;
  constexpr int ROWS = 36, LDSTRIDE = 136;
  __shared__ ushort_t sA[ROWS * LDSTRIDE];

  const int b = mt >> 4, t0 = (mt & 15) * 32;
  const int tid = threadIdx.x;
  const int l = tid & 63, nh = tid >> 6;
  const int lm = l & 31, lq = l >> 5;
  const int cob32 = ns * 4 + nh;

  f32x16 acc;
#pragma unroll
  for (int i = 0; i < 16; ++i) acc[i] = 0.f;

  const ushort_t* pB = wB + (size_t)cob32 * 512 + l * 8;

#pragma unroll 1
  for (int chunk = 0; chunk < NCHUNK; ++chunk) {
    {
      const int cibase = chunk * 128;
#pragma unroll 1
      for (int i = 0; i < 9; ++i) {
        const int p = i * 256 + tid;      // 9*256 = 2304 = 36*64 exact
        const int r = p >> 6, c2 = (p & 63) * 2;
        const int t = t0 - 2 + r;
        unsigned hv = 0;
        if ((unsigned)t < (unsigned)Tn) {
          const size_t src = (size_t)(b * Tn + t) * CI + cibase + c2;
          if (F32IN) {
            const float2 v = *(const float2*)(xin + src);
            hv = (unsigned)f2bf(v.x) | ((unsigned)f2bf(v.y) << 16);
          } else {
            hv = *(const unsigned*)(inbf + src);
          }
        }
        const int sw = ((r >> 3) & 3) << 3;
        *(unsigned*)&sA[r * LDSTRIDE + (c2 ^ sw)] = hv;
      }
    }
    __syncthreads();

#pragma unroll 1
    for (int ksh = 0; ksh < 5; ++ksh) {
      const int r = lm + ksh;
      const int sw = ((r >> 3) & 3) << 3;
      const size_t bbase = (size_t)((ksh * (CI / 16) + chunk * 8) * 8) * 512;
#pragma unroll
      for (int kk = 0; kk < 8; ++kk) {
        const int c = (kk * 16 + lq * 8) ^ sw;
        const bf16x8 a = *(const bf16x8*)&sA[r * LDSTRIDE + c];
        const bf16x8 bv = *(const bf16x8*)(pB + bbase + (size_t)kk * 8 * 512);
        acc = __builtin_amdgcn_mfma_f32_32x32x16_bf16(a, bv, acc, 0, 0, 0);
      }
    }
    __syncthreads();
  }

  // D: col = lane&31, row = (reg&3) + 8*(reg>>2) + 4*(lane>>5)
  const int col = ns * 128 + nh * 32 + lm;
  float* pOut = hraw + (size_t)(b * Tn + t0) * 256 + col;
#pragma unroll
  for (int reg = 0; reg < 16; ++reg) {
    const int row = (reg & 3) + 8 * (reg >> 2) + 4 * lq;
    pOut[(size_t)row * 256] = acc[reg];
  }
}

// ---------------------------------------------------------------------------
// Dispatch 2: conv1 (blk%3==0, 512 blocks) + x_up gather (1024 blocks).
// Grid 1536. Interleaved so each CU's co-resident set mixes both types.
// ---------------------------------------------------------------------------
__global__ __launch_bounds__(256, 2) void conv1_gather_kernel(
    const float* __restrict__ x_res, const ushort_t* __restrict__ w1,
    float* __restrict__ hraw,
    const float* __restrict__ x, const int* __restrict__ idx,
    float* __restrict__ x_up) {
  const int blk = blockIdx.x;
  if (blk % 3 == 0) {
    const int cid = blk / 3;              // 0..511
    conv_body<512, true>(cid & 255, cid >> 8, x_res, nullptr, w1, hraw);
    return;
  }
  // ---- x_up gather: 1024 blocks, 2,097,152 f32x4 units (8 iters) ----
  const int gid = blk - 1 - blk / 3;      // 0..1023
  const f32x4* x4 = (const f32x4*)x;
  f32x4* xu4 = (f32x4*)x_up;
  const int tid0 = gid * 256 + threadIdx.x;
  const int stride = 1024 * 256;
  const f32x4 z = (f32x4){0.f, 0.f, 0.f, 0.f};
  for (int u = tid0; u < Bn * MAXMEL * 128; u += stride) {
    const int bp = u >> 7, i = u & 127;
    const int t = idx[bp];
    const int b = bp >> 12;
    const f32x4 v = (t >= 0) ? x4[((b << 9) + t) * 128 + i] : z;
    __builtin_nontemporal_store(v, &xu4[u]);
  }
}

// ---------------------------------------------------------------------------
// Dispatch 4: conv2 (blk%3==0, 512 blocks) + emb_up gather (1024 blocks).
// ---------------------------------------------------------------------------
__global__ __launch_bounds__(256, 2) void conv2_gather_kernel(
    const ushort_t* __restrict__ h1, const ushort_t* __restrict__ w2,
    float* __restrict__ hraw,
    const float* __restrict__ emb, const int* __restrict__ idx,
    float* __restrict__ emb_up) {
  const int blk = blockIdx.x;
  if (blk % 3 == 0) {
    const int cid = blk / 3;
    conv_body<256, false>(cid & 255, cid >> 8, nullptr, h1, w2, hraw);
    return;
  }
  // ---- emb_up gather: 1024 blocks, 1,572,864 f32x4 units (6 iters) ----
  const int gid = blk - 1 - blk / 3;
  const f32x4* e4 = (const f32x4*)emb;
  f32x4* eu4 = (f32x4*)emb_up;
  const int tid0 = gid * 256 + threadIdx.x;
  const int stride = 1024 * 256;
  const f32x4 z = (f32x4){0.f, 0.f, 0.f, 0.f};
  for (int u = tid0; u < Bn * MAXMEL * 96; u += stride) {
    const int bp = u / 96, i = u - bp * 96;
    const int t = idx[bp];
    const int b = bp >> 12;
    const f32x4 v = (t >= 0) ? e4[((b << 9) + t) * 96 + i] : z;
    __builtin_nontemporal_store(v, &eu4[u]);
  }
}

// ---------------------------------------------------------------------------
// bias + leaky-relu + LayerNorm. One wave per row, grid 2048.
// FINAL=false: emit h1 bf16. FINAL=true: fused linear(256->1) + mask -> ldp.
// ---------------------------------------------------------------------------
template <bool FINAL>
__global__ __launch_bounds__(256) void ln_kernel(
    const float* __restrict__ hraw,       // [8192][256] f32
    const float* __restrict__ bias, const float* __restrict__ g,
    const float* __restrict__ be, ushort_t* __restrict__ h1,
    const float* __restrict__ lw, const float* __restrict__ lb,
    const unsigned char* __restrict__ mask, float* __restrict__ ldp) {
  const int row = blockIdx.x * 4 + (threadIdx.x >> 6);
  const int l = threadIdx.x & 63;
  const f32x4 p = ((const f32x4*)hraw)[row * 64 + l];
  const f32x4 bi = ((const f32x4*)bias)[l];
  float v0 = p.x + bi.x, v1 = p.y + bi.y, v2 = p.z + bi.z, v3 = p.w + bi.w;
  v0 = (v0 > 0.f) ? v0 : LRELU * v0;
  v1 = (v1 > 0.f) ? v1 : LRELU * v1;
  v2 = (v2 > 0.f) ? v2 : LRELU * v2;
  v3 = (v3 > 0.f) ? v3 : LRELU * v3;
  float s = v0 + v1 + v2 + v3;
  float s2 = v0 * v0 + v1 * v1 + v2 * v2 + v3 * v3;
#pragma unroll
  for (int off = 32; off >= 1; off >>= 1) {
    s += __shfl_xor(s, off);
    s2 += __shfl_xor(s2, off);
  }
  const float mu = s * (1.f / 256.f);
  const float var = s2 * (1.f / 256.f) - mu * mu;
  const float rs = rsqrtf(var + EPSV);
  const f32x4 gg = ((const f32x4*)g)[l];
  const f32x4 bb = ((const f32x4*)be)[l];
  const float h0 = (v0 - mu) * rs * gg.x + bb.x;
  const float h1v = (v1 - mu) * rs * gg.y + bb.y;
  const float h2 = (v2 - mu) * rs * gg.z + bb.z;
  const float h3 = (v3 - mu) * rs * gg.w + bb.w;
  if (!FINAL) {
    ushort4 uh;
    uh.x = f2bf(h0); uh.y = f2bf(h1v); uh.z = f2bf(h2); uh.w = f2bf(h3);
    ((ushort4*)h1)[row * 64 + l] = uh;
  } else {
    const f32x4 lv = ((const f32x4*)lw)[l];
    float d = h0 * lv.x + h1v * lv.y + h2 * lv.z + h3 * lv.w;
#pragma unroll
    for (int off = 32; off >= 1; off >>= 1) d += __shfl_xor(d, off);
    if (l == 0) {
      float val = d + lb[0];
      if (mask[row]) val = 0.f;
      ldp[row] = val;
    }
  }
}

// ---------------------------------------------------------------------------
// Dispatch 1: weight prep (blocks 0..239, 8 frags/block) + build_idx
// (blocks 240..255). 512 threads.
// ---------------------------------------------------------------------------
__global__ __launch_bounds__(512) void prep_kernel(
    const float* __restrict__ w1src, const float* __restrict__ w2src,
    ushort_t* __restrict__ w1dst, ushort_t* __restrict__ w2dst,
    const int* __restrict__ dur, int* __restrict__ idx) {
  __shared__ int wsum[8];
  const int blk = blockIdx.x;
  const int tid = threadIdx.x;
  if (blk < 240) {
    const float* src;
    ushort_t* dst;
    int CI, fr, sh;
    const int wv = tid >> 6, l = tid & 63;
    if (blk < 160) { src = w1src; dst = w1dst; CI = 512; sh = 5; fr = blk * 8 + wv; }
    else           { src = w2src; dst = w2dst; CI = 256; sh = 4; fr = (blk - 160) * 8 + wv; }
    const int cob32 = fr & 7;
    const int t = fr >> 3;
    const int ksh = t >> sh;
    const int ci16 = t & ((1 << sh) - 1);
    const int ci = ci16 * 16 + (l >> 5) * 8;
    const int co = cob32 * 32 + (l & 31);
    ushort_t v[8];
#pragma unroll
    for (int j = 0; j < 8; ++j)
      v[j] = f2bf(src[((size_t)(ksh * CI + ci + j)) * 256 + co]);
    u32x4 pack;
#pragma unroll
    for (int q = 0; q < 4; ++q)
      pack[q] = (unsigned)v[q * 2] | ((unsigned)v[q * 2 + 1] << 16);
    *(u32x4*)&dst[(size_t)fr * 512 + l * 8] = pack;
    return;
  }
  // ---- build_idx path ----
  const int b = blk - 240;
  const int lane = tid & 63, wv = tid >> 6;
  const int d = dur[b * Tn + tid];
  int v = d;
#pragma unroll
  for (int off = 1; off <= 32; off <<= 1) {
    const int t = __shfl_up(v, off);
    if (lane >= off) v += t;
  }
  if (lane == 63) wsum[wv] = v;
  __syncthreads();
  int woff = 0, total = 0;
#pragma unroll
  for (int i = 0; i < 8; ++i) {
    const int s = wsum[i];
    if (i < wv) woff += s;
    total += s;
  }
  const int end = v + woff;               // inclusive cumsum
  for (int p = end - d; p < end; ++p) idx[b * MAXMEL + p] = tid;
  for (int p = total + tid; p < MAXMEL; p += 512) idx[b * MAXMEL + p] = -1;
}

// ---------------------------------------------------------------------------
extern "C" void kernel_launch(void* const* d_in, const int* in_sizes, int n_in,
                              void* d_out, int out_size, void* d_ws, size_t ws_size,
                              hipStream_t stream) {
  const float* x     = (const float*)d_in[0];
  const float* x_res = (const float*)d_in[1];
  const int*   dur   = (const int*)d_in[2];
  const float* emb   = (const float*)d_in[3];
  const unsigned char* mask = (const unsigned char*)d_in[4];
  const float* c1w = (const float*)d_in[5];
  const float* c1b = (const float*)d_in[6];
  const float* g1  = (const float*)d_in[7];
  const float* b1  = (const float*)d_in[8];
  const float* c2w = (const float*)d_in[9];
  const float* c2b = (const float*)d_in[10];
  const float* g2  = (const float*)d_in[11];
  const float* b2  = (const float*)d_in[12];
  const float* lw  = (const float*)d_in[13];
  const float* lb  = (const float*)d_in[14];

  float* x_up   = (float*)d_out;
  float* ldp    = x_up + (size_t)Bn * MAXMEL * CIN1;
  float* emb_up = ldp + (size_t)Bn * Tn;

  // ws layout: idx 256KB | h1 4MB | w1 1.31MB | w2 0.66MB | hraw 8MB ≈ 14.5MB
  int* idx = (int*)d_ws;
  ushort_t* h1 = (ushort_t*)((char*)d_ws + (size_t)Bn * MAXMEL * 4);
  ushort_t* w1 = h1 + (size_t)NROWS * 256;
  ushort_t* w2 = w1 + (size_t)5 * 512 * 256;
  float* hraw = (float*)(w2 + (size_t)5 * 256 * 256);

  prep_kernel<<<256, 512, 0, stream>>>(c1w, c2w, w1, w2, dur, idx);
  conv1_gather_kernel<<<1536, 256, 0, stream>>>(
      x_res, w1, hraw, x, idx, x_up);
  ln_kernel<false><<<NROWS / 4, 256, 0, stream>>>(
      hraw, c1b, g1, b1, h1, nullptr, nullptr, nullptr, nullptr);
  conv2_gather_kernel<<<1536, 256, 0, stream>>>(
      h1, w2, hraw, emb, idx, emb_up);
  ln_kernel<true><<<NROWS / 4, 256, 0, stream>>>(
      hraw, c2b, g2, b2, nullptr, lw, lb, mask, ldp);
}